// Round 6
// baseline (574.778 us; speedup 1.0000x reference)
//
#include <hip/hip_runtime.h>
#include <hip/hip_bf16.h>
#include <cstdint>
#include <cstddef>

// ---------- types ----------
typedef __bf16 bf16_t;
typedef __bf16 bf16x8 __attribute__((ext_vector_type(8)));
typedef __bf16 bf16x4 __attribute__((ext_vector_type(4)));
typedef float  f32x4  __attribute__((ext_vector_type(4)));

#define DIM    1024
#define NCOEF  8
#define KTOT   (DIM + DIM * NCOEF)   // 9216
#define NKNOT  12
#define BATCH  8192
#define LN_EPS 1e-5f

// ---------- device helpers ----------
__device__ __forceinline__ float gelu_exact(float x) {
    return 0.5f * x * (1.0f + erff(x * 0.70710678118654752440f));
}

__device__ __forceinline__ void gl_lds16(const void* g, void* l) {
    __builtin_amdgcn_global_load_lds(
        (const __attribute__((address_space(1))) unsigned int*)(uintptr_t)g,
        (__attribute__((address_space(3))) unsigned int*)(uintptr_t)l, 16, 0, 0);
}

__device__ __forceinline__ uint64_t pack4bf(float a, float b, float c, float d) {
    union { bf16_t h[4]; uint64_t q; } u;
    u.h[0] = (bf16_t)a; u.h[1] = (bf16_t)b; u.h[2] = (bf16_t)c; u.h[3] = (bf16_t)d;
    return u.q;
}

// Uniform cubic B-spline: 8 bf16 bases of one feature as 16 bytes (lo,hi).
__device__ __forceinline__ void spline8(float x, float g0, float invh,
                                        uint64_t& lo, uint64_t& hi) {
    float u = (x - g0) * invh;
    float jf = floorf(u);
    int j = (int)jf;
    float f = u - jf;
    float f2 = f * f, f3 = f2 * f;
    float om = 1.0f - f, om2 = om * om;
    float w0 = om2 * om * (1.0f / 6.0f);
    float w3 = f3 * (1.0f / 6.0f);
    float w1 = fmaf(0.5f, f3, 2.0f / 3.0f) - f2;
    float w2 = 1.0f - w0 - w1 - w3;
    uint64_t W64 = pack4bf(w0, w1, w2, w3);
    if (!(u >= 0.0f && u < 11.0f)) W64 = 0;
    int sh = (j - 3) * 16;
    if (sh >= 0) {
        int s = sh & 63;
        uint64_t loW = W64 << s;
        uint64_t hiW = s ? (W64 >> (64 - s)) : 0ull;
        lo = (sh < 64) ? loW : 0ull;
        hi = (sh < 64) ? hiW : loW;
    } else {
        lo = W64 >> (-sh);
        hi = 0ull;
    }
}

// ---------- W pack: [base_w | spline_w] f32 -> bf16, K-packed ----------
__global__ void pack_w(const float* __restrict__ bw, const float* __restrict__ sw,
                       bf16_t* __restrict__ W) {
    int idx = blockIdx.x * 256 + threadIdx.x;      // (layer,o,j)
    bf16_t* wrow = W + (size_t)(idx >> 10) * KTOT;
    int j = idx & 1023;
    wrow[j] = (bf16_t)bw[idx];
    const float4* sp = (const float4*)(sw + (size_t)idx * NCOEF);
    float4 s0 = sp[0], s1 = sp[1];
    bf16x8 v;
    v[0] = (bf16_t)s0.x; v[1] = (bf16_t)s0.y; v[2] = (bf16_t)s0.z; v[3] = (bf16_t)s0.w;
    v[4] = (bf16_t)s1.x; v[5] = (bf16_t)s1.y; v[6] = (bf16_t)s1.z; v[7] = (bf16_t)s1.w;
    *(bf16x8*)(wrow + DIM + j * NCOEF) = v;
}

// ---------- layer-0 A build: A[row] = [gelu(x) bf16 x1024 | bases bf16 x8192] ----------
__global__ void prep_A(const float* __restrict__ x, bf16_t* __restrict__ A,
                       const float* __restrict__ gp, int R) {
    const int t = threadIdx.x;
    const float g0 = gp[0];
    const float invh = 1.0f / (gp[1] - gp[0]);
    for (int row = blockIdx.x; row < R; row += gridDim.x) {
        f32x4 v = *(const f32x4*)(x + (size_t)row * DIM + t * 4);
        bf16_t* Ar = A + (size_t)row * KTOT;
        bf16x4 ge;
#pragma unroll
        for (int k = 0; k < 4; k++) ge[k] = (bf16_t)gelu_exact(v[k]);
        *(bf16x4*)(Ar + t * 4) = ge;
#pragma unroll
        for (int k = 0; k < 4; k++) {
            uint64_t lo, hi;
            union { uint64_t u[2]; uint4 q; } o;
            spline8(v[k], g0, invh, lo, hi);
            o.u[0] = lo; o.u[1] = hi;
            *(uint4*)(Ar + DIM + (t * 4 + k) * NCOEF) = o.q;
        }
    }
}

// =====================================================================
// Dense GEMM, copy-free register-fragment pipeline:
// BM=BN=256, BK=32, 8 waves (128x64 each), 4-slot LDS, prefetch 3 tiles.
// Even/odd frag register sets alternate via accessor-macro parameters
// (EA/EB/OA/OB) -> no rotation copies -> no forced lgkmcnt(0) drain.
// Per tile t (slot S=t&3, next SN=(t+1)&3, stage SP=(t+3)&3):
//  PA: stage A(t+3); read CA(4..7) from slot S; lgkm(4) [drains the 8
//      early reads issued during prev tile's PB]; 16 MFMA rows0-3
//  PB: stage B(t+3); vmcnt(8) [tile t+1 resident]; BAR; read NA(0..3),
//      NB(0..3) from slot SN; lgkm(8) [drains CA(4..7) only; the 8 new
//      reads stay in flight under this + next MFMA cluster]; 16 MFMA
//      rows4-7; BAR
// 2 barriers/tile. All waits counted; sched_barrier(0) after each wait.
// =====================================================================

#define STR2(x) #x
#define GATEV(N) asm volatile("s_waitcnt vmcnt(" STR2(N) ")" ::: "memory");
#define LGKM(N)  asm volatile("s_waitcnt lgkmcnt(" STR2(N) ")" ::: "memory");
#define BAR() { __builtin_amdgcn_s_barrier(); asm volatile("" ::: "memory"); }

#define EA(i) ea##i
#define EB(i) eb##i
#define OA(i) oa##i
#define OB(i) ob##i

#define MF_ROWX(I, A_, CB) \
    acc[I][0] = __builtin_amdgcn_mfma_f32_16x16x32_bf16(A_, CB(0), acc[I][0], 0, 0, 0); \
    acc[I][1] = __builtin_amdgcn_mfma_f32_16x16x32_bf16(A_, CB(1), acc[I][1], 0, 0, 0); \
    acc[I][2] = __builtin_amdgcn_mfma_f32_16x16x32_bf16(A_, CB(2), acc[I][2], 0, 0, 0); \
    acc[I][3] = __builtin_amdgcn_mfma_f32_16x16x32_bf16(A_, CB(3), acc[I][3], 0, 0, 0);

#define TILE(T, S, SN, SP, STG, GATESTMT, RD, WAITB, CA, CB, NA, NB) { \
    /* ---- PA ---- */ \
    if (STG) { \
      gl_lds16(Ag0 + (size_t)((T) + 3) * 32, ldsA + (SP) * 8192 + tid * 8); \
      gl_lds16(Ag1 + (size_t)((T) + 3) * 32, ldsA + (SP) * 8192 + 4096 + tid * 8); } \
    { const bf16_t* Ab_ = ldsA + (S) * 8192 + aOff; \
      CA(4) = *(const bf16x8*)(Ab_ + 2048); CA(5) = *(const bf16x8*)(Ab_ + 2560); \
      CA(6) = *(const bf16x8*)(Ab_ + 3072); CA(7) = *(const bf16x8*)(Ab_ + 3584); } \
    LGKM(4) \
    __builtin_amdgcn_sched_barrier(0); \
    __builtin_amdgcn_s_setprio(1); \
    MF_ROWX(0, CA(0), CB) MF_ROWX(1, CA(1), CB) \
    MF_ROWX(2, CA(2), CB) MF_ROWX(3, CA(3), CB) \
    __builtin_amdgcn_s_setprio(0); \
    /* ---- PB ---- */ \
    if (STG) { \
      gl_lds16(Bg0 + (size_t)((T) + 3) * 32, ldsB + (SP) * 8192 + tid * 8); \
      gl_lds16(Bg1 + (size_t)((T) + 3) * 32, ldsB + (SP) * 8192 + 4096 + tid * 8); } \
    GATESTMT \
    if (RD) { \
      BAR() \
      const bf16_t* An_ = ldsA + (SN) * 8192 + aOff; \
      const bf16_t* Bn_ = ldsB + (SN) * 8192 + bOff; \
      NA(0) = *(const bf16x8*)(An_);        NA(1) = *(const bf16x8*)(An_ + 512); \
      NA(2) = *(const bf16x8*)(An_ + 1024); NA(3) = *(const bf16x8*)(An_ + 1536); \
      NB(0) = *(const bf16x8*)(Bn_);        NB(1) = *(const bf16x8*)(Bn_ + 512); \
      NB(2) = *(const bf16x8*)(Bn_ + 1024); NB(3) = *(const bf16x8*)(Bn_ + 1536); } \
    WAITB \
    __builtin_amdgcn_sched_barrier(0); \
    __builtin_amdgcn_s_setprio(1); \
    MF_ROWX(4, CA(4), CB) MF_ROWX(5, CA(5), CB) \
    MF_ROWX(6, CA(6), CB) MF_ROWX(7, CA(7), CB) \
    __builtin_amdgcn_s_setprio(0); \
    BAR() \
}

#define PSTAGE(T, S) \
    gl_lds16(Ag0 + (size_t)(T) * 32, ldsA + (S) * 8192 + tid * 8); \
    gl_lds16(Ag1 + (size_t)(T) * 32, ldsA + (S) * 8192 + 4096 + tid * 8); \
    gl_lds16(Bg0 + (size_t)(T) * 32, ldsB + (S) * 8192 + tid * 8); \
    gl_lds16(Bg1 + (size_t)(T) * 32, ldsB + (S) * 8192 + 4096 + tid * 8);

template<int NTK>
__global__ __launch_bounds__(512, 2) void gemm_ab(
    const bf16_t* __restrict__ A,      // [rows, 9216] bf16
    const bf16_t* __restrict__ W,      // [1024, 9216] bf16
    float* __restrict__ C,             // [ksplit, rows, 1024] f32 partials
    int mmask, int mshift, int rows) {
    __shared__ __align__(16) bf16_t lds[65536];    // 128 KB
    bf16_t* __restrict__ ldsA = lds;
    bf16_t* __restrict__ ldsB = lds + 32768;

    const int tid = threadIdx.x;
    const int l = tid & 63, wv = tid >> 6;
    const int wm = wv >> 2, wn = wv & 3;           // 2M x 4N waves, 128x64 each

    // XCD-aware swizzle (grid always divisible by 8)
    const int chunk = gridDim.x >> 3;
    const int bid = blockIdx.x;
    const int wg = (bid & 7) * chunk + (bid >> 3);
    const int bm = wg & mmask;
    const int bn = (wg >> mshift) & 3;
    const int ks = wg >> (mshift + 2);
    const int row0 = bm << 8, col0 = bn << 8;
    const int koff0 = ks * (NTK * 32);

    // staging: thread covers rows srow, srow+128; source pre-swizzled by chunk
    const int srow = tid >> 2;
    const int slc = (tid & 3) ^ ((srow >> 1) & 3);
    const bf16_t* __restrict__ Ag0 = A + (size_t)(row0 + srow) * KTOT + koff0 + slc * 8;
    const bf16_t* __restrict__ Ag1 = Ag0 + (size_t)128 * KTOT;
    const bf16_t* __restrict__ Bg0 = W + (size_t)(col0 + srow) * KTOT + koff0 + slc * 8;
    const bf16_t* __restrict__ Bg1 = Bg0 + (size_t)128 * KTOT;

    // fragment-read offsets; physical chunk = logical(l>>4) ^ ((row>>1)&3)
    const int l15 = l & 15;
    const int pc = (l >> 4) ^ ((l15 >> 1) & 3);
    const int aOff = (wm * 128 + l15) * 32 + pc * 8;
    const int bOff = (wn * 64 + l15) * 32 + pc * 8;

    f32x4 acc[8][4] = {};
    bf16x8 ea0, ea1, ea2, ea3, ea4, ea5, ea6, ea7, eb0, eb1, eb2, eb3;
    bf16x8 oa0, oa1, oa2, oa3, oa4, oa5, oa6, oa7, ob0, ob1, ob2, ob3;

    // prologue: tiles 0,1,2 staged (12 vm ops); drain tile 0; read its batch1
    PSTAGE(0, 0)
    PSTAGE(1, 1)
    PSTAGE(2, 2)
    GATEV(8)
    BAR()
    {
        const bf16_t* An_ = ldsA + aOff;
        const bf16_t* Bn_ = ldsB + bOff;
        ea0 = *(const bf16x8*)(An_);        ea1 = *(const bf16x8*)(An_ + 512);
        ea2 = *(const bf16x8*)(An_ + 1024); ea3 = *(const bf16x8*)(An_ + 1536);
        eb0 = *(const bf16x8*)(Bn_);        eb1 = *(const bf16x8*)(Bn_ + 512);
        eb2 = *(const bf16x8*)(Bn_ + 1024); eb3 = *(const bf16x8*)(Bn_ + 1536);
    }

#pragma unroll 1
    for (int t = 0; t < NTK - 4; t += 4) {
        TILE(t + 0, 0, 1, 3, 1, GATEV(8), 1, LGKM(8), EA, EB, OA, OB)
        TILE(t + 1, 1, 2, 0, 1, GATEV(8), 1, LGKM(8), OA, OB, EA, EB)
        TILE(t + 2, 2, 3, 1, 1, GATEV(8), 1, LGKM(8), EA, EB, OA, OB)
        TILE(t + 3, 3, 0, 2, 1, GATEV(8), 1, LGKM(8), OA, OB, EA, EB)
    }
    TILE(NTK - 4, 0, 1, 3, 1, GATEV(8), 1, LGKM(8), EA, EB, OA, OB)
    TILE(NTK - 3, 1, 2, 0, 0, GATEV(4), 1, LGKM(8), OA, OB, EA, EB)
    TILE(NTK - 2, 2, 3, 1, 0, GATEV(0), 1, LGKM(8), EA, EB, OA, OB)
    TILE(NTK - 1, 3, 0, 2, 0, GATEV(0), 0, LGKM(0), OA, OB, EA, EB)

    float* __restrict__ Cp = C + (size_t)ks * rows * DIM;
    const int r0 = row0 + wm * 128 + (l >> 4) * 4;
    const int c0 = col0 + wn * 64 + l15;
#pragma unroll
    for (int i = 0; i < 8; i++)
#pragma unroll
        for (int j = 0; j < 4; j++)
#pragma unroll
            for (int r = 0; r < 4; r++)
                Cp[(size_t)(r0 + i * 16 + r) * DIM + c0 + j * 16] = acc[i][j][r];
}

// ---------- LN + PReLU over summed partials -> next-layer A (gelu + bases) ----------
__global__ void ln_mid_A(const float* __restrict__ h, int rows, int ksplit,
                         const float* __restrict__ g_ln, const float* __restrict__ b_ln,
                         const float* __restrict__ pa, bf16_t* __restrict__ A,
                         const float* __restrict__ gp) {
    const int tid = threadIdx.x;
    const int w = tid >> 6, l = tid & 63;
    const float a = pa[0];
    const float g0 = gp[0];
    const float invh = 1.0f / (gp[1] - gp[0]);
    __shared__ float rs[4], rq[4];
    for (int row = blockIdx.x; row < rows; row += gridDim.x) {
        f32x4 v = {0.0f, 0.0f, 0.0f, 0.0f};
        for (int ks = 0; ks < ksplit; ks++)
            v += *(const f32x4*)(h + ((size_t)ks * rows + row) * DIM + tid * 4);
        float s = v[0] + v[1] + v[2] + v[3];
        float q = v[0] * v[0] + v[1] * v[1] + v[2] * v[2] + v[3] * v[3];
#pragma unroll
        for (int o = 32; o > 0; o >>= 1) { s += __shfl_xor(s, o); q += __shfl_xor(q, o); }
        if (l == 0) { rs[w] = s; rq[w] = q; }
        __syncthreads();
        s = rs[0] + rs[1] + rs[2] + rs[3];
        q = rq[0] + rq[1] + rq[2] + rq[3];
        __syncthreads();
        float mean = s * (1.0f / DIM);
        float var = q * (1.0f / DIM) - mean * mean;
        float rstd = rsqrtf(var + LN_EPS);
        bf16_t* Ar = A + (size_t)row * KTOT;
        bf16x4 ge;
#pragma unroll
        for (int c = 0; c < 4; c++) {
            int col = tid * 4 + c;
            float yv = (v[c] - mean) * rstd * g_ln[col] + b_ln[col];
            yv = (yv >= 0.0f) ? yv : a * yv;
            ge[c] = (bf16_t)gelu_exact(yv);
            uint64_t lo, hi;
            union { uint64_t u[2]; uint4 qv; } o;
            spline8(yv, g0, invh, lo, hi);
            o.u[0] = lo; o.u[1] = hi;
            *(uint4*)(Ar + DIM + (size_t)col * NCOEF) = o.qv;
        }
        *(bf16x4*)(Ar + tid * 4) = ge;
    }
}

// ---------- final LN + PReLU -> f32 out ----------
__global__ void ln_out(const float* __restrict__ h, int rows, int ksplit,
                       const float* __restrict__ g_ln, const float* __restrict__ b_ln,
                       const float* __restrict__ pa, float* __restrict__ out) {
    const int tid = threadIdx.x;
    const int w = tid >> 6, l = tid & 63;
    const float a = pa[0];
    __shared__ float rs[4], rq[4];
    for (int row = blockIdx.x; row < rows; row += gridDim.x) {
        f32x4 v = {0.0f, 0.0f, 0.0f, 0.0f};
        for (int ks = 0; ks < ksplit; ks++)
            v += *(const f32x4*)(h + ((size_t)ks * rows + row) * DIM + tid * 4);
        float s = v[0] + v[1] + v[2] + v[3];
        float q = v[0] * v[0] + v[1] * v[1] + v[2] * v[2] + v[3] * v[3];
#pragma unroll
        for (int o = 32; o > 0; o >>= 1) { s += __shfl_xor(s, o); q += __shfl_xor(q, o); }
        if (l == 0) { rs[w] = s; rq[w] = q; }
        __syncthreads();
        s = rs[0] + rs[1] + rs[2] + rs[3];
        q = rq[0] + rq[1] + rq[2] + rq[3];
        __syncthreads();
        float mean = s * (1.0f / DIM);
        float var = q * (1.0f / DIM) - mean * mean;
        float rstd = rsqrtf(var + LN_EPS);
        f32x4 o4;
#pragma unroll
        for (int c = 0; c < 4; c++) {
            int col = tid * 4 + c;
            float yv = (v[c] - mean) * rstd * g_ln[col] + b_ln[col];
            o4[c] = (yv >= 0.0f) ? yv : a * yv;
        }
        *(f32x4*)(out + (size_t)row * DIM + tid * 4) = o4;
    }
}

// ---------- launch ----------
extern "C" void kernel_launch(void* const* d_in, const int* in_sizes, int n_in,
                              void* d_out, int out_size, void* d_ws, size_t ws_size,
                              hipStream_t stream) {
    const float* x    = (const float*)d_in[0];
    const float* bw   = (const float*)d_in[1];
    const float* sw   = (const float*)d_in[2];
    const float* ln_g = (const float*)d_in[3];
    const float* ln_b = (const float*)d_in[4];
    const float* pa   = (const float*)d_in[5];
    const float* gridK = (const float*)d_in[6];
    float* out = (float*)d_out;

    const size_t wbytes = (size_t)2 * DIM * KTOT * sizeof(bf16_t);   // 37.75 MB
    // per-slab: A = R*9216*2 B, hbuf = ksplit*R*1024*4 B
    int R = 8192, ksplit = 2;
    for (;;) {
        size_t need = wbytes + (size_t)R * KTOT * 2 + (size_t)ksplit * R * DIM * 4;
        if (need <= ws_size || R == 512) break;
        R >>= 1;
        int mt = R / 256;
        ksplit = (mt >= 32) ? 2 : (mt >= 16) ? 4 : 8;
    }
    int mtiles = R / 256;
    int mshift = 0; while ((1 << mshift) < mtiles) mshift++;
    int mmask = mtiles - 1;
    int grid = mtiles * 4 * ksplit;
    int lng = (R >= 2048) ? 2048 : R;

    char* wsc = (char*)d_ws;
    bf16_t* Wbuf = (bf16_t*)wsc;
    bf16_t* Abuf = (bf16_t*)(wsc + wbytes);
    float*  hbuf = (float*)(wsc + wbytes + (size_t)R * KTOT * 2);

    pack_w<<<(2 * DIM * DIM) / 256, 256, 0, stream>>>(bw, sw, Wbuf);

    auto launch_gemm = [&](const bf16_t* Wl, hipStream_t st) {
        if (ksplit == 2)
            gemm_ab<144><<<grid, 512, 0, st>>>(Abuf, Wl, hbuf, mmask, mshift, R);
        else if (ksplit == 4)
            gemm_ab<72><<<grid, 512, 0, st>>>(Abuf, Wl, hbuf, mmask, mshift, R);
        else
            gemm_ab<36><<<grid, 512, 0, st>>>(Abuf, Wl, hbuf, mmask, mshift, R);
    };

    const int nslab = BATCH / R;
    for (int sidx = 0; sidx < nslab; sidx++) {
        const size_t row0 = (size_t)sidx * R;
        const float* x0 = x + row0 * DIM;
        // layer 0
        prep_A<<<lng, 256, 0, stream>>>(x0, Abuf, gridK, R);
        launch_gemm(Wbuf, stream);
        ln_mid_A<<<lng, 256, 0, stream>>>(hbuf, R, ksplit, ln_g, ln_b, pa,
                                          Abuf, gridK + DIM * NKNOT);
        // layer 1
        launch_gemm(Wbuf + (size_t)DIM * KTOT, stream);
        ln_out<<<lng, 256, 0, stream>>>(hbuf, R, ksplit, ln_g + DIM, ln_b + DIM,
                                        pa + 1, out + row0 * DIM);
    }
}

// Round 7
// 512.190 us; speedup vs baseline: 1.1222x; 1.1222x over previous
//
#include <hip/hip_runtime.h>
#include <hip/hip_bf16.h>
#include <cstdint>
#include <cstddef>

// ---------- types ----------
typedef __bf16 bf16_t;
typedef __bf16 bf16x8 __attribute__((ext_vector_type(8)));
typedef __bf16 bf16x4 __attribute__((ext_vector_type(4)));
typedef float  f32x4  __attribute__((ext_vector_type(4)));

#define DIM    1024
#define NCOEF  8
#define KTOT   (DIM + DIM * NCOEF)   // 9216
#define NKNOT  12
#define BATCH  8192
#define LN_EPS 1e-5f

// ---------- device helpers ----------
__device__ __forceinline__ float gelu_exact(float x) {
    return 0.5f * x * (1.0f + erff(x * 0.70710678118654752440f));
}

__device__ __forceinline__ void gl_lds16(const void* g, void* l) {
    __builtin_amdgcn_global_load_lds(
        (const __attribute__((address_space(1))) unsigned int*)(uintptr_t)g,
        (__attribute__((address_space(3))) unsigned int*)(uintptr_t)l, 16, 0, 0);
}

__device__ __forceinline__ uint64_t pack4bf(float a, float b, float c, float d) {
    union { bf16_t h[4]; uint64_t q; } u;
    u.h[0] = (bf16_t)a; u.h[1] = (bf16_t)b; u.h[2] = (bf16_t)c; u.h[3] = (bf16_t)d;
    return u.q;
}

// Uniform cubic B-spline: 8 bf16 bases of one feature as 16 bytes (lo,hi).
__device__ __forceinline__ void spline8(float x, float g0, float invh,
                                        uint64_t& lo, uint64_t& hi) {
    float u = (x - g0) * invh;
    float jf = floorf(u);
    int j = (int)jf;
    float f = u - jf;
    float f2 = f * f, f3 = f2 * f;
    float om = 1.0f - f, om2 = om * om;
    float w0 = om2 * om * (1.0f / 6.0f);
    float w3 = f3 * (1.0f / 6.0f);
    float w1 = fmaf(0.5f, f3, 2.0f / 3.0f) - f2;
    float w2 = 1.0f - w0 - w1 - w3;
    uint64_t W64 = pack4bf(w0, w1, w2, w3);
    if (!(u >= 0.0f && u < 11.0f)) W64 = 0;
    int sh = (j - 3) * 16;
    if (sh >= 0) {
        int s = sh & 63;
        uint64_t loW = W64 << s;
        uint64_t hiW = s ? (W64 >> (64 - s)) : 0ull;
        lo = (sh < 64) ? loW : 0ull;
        hi = (sh < 64) ? hiW : loW;
    } else {
        lo = W64 >> (-sh);
        hi = 0ull;
    }
}

// ---------- W pack: [base_w | spline_w] f32 -> bf16, K-packed ----------
__global__ void pack_w(const float* __restrict__ bw, const float* __restrict__ sw,
                       bf16_t* __restrict__ W) {
    int idx = blockIdx.x * 256 + threadIdx.x;      // (layer,o,j)
    bf16_t* wrow = W + (size_t)(idx >> 10) * KTOT;
    int j = idx & 1023;
    wrow[j] = (bf16_t)bw[idx];
    const float4* sp = (const float4*)(sw + (size_t)idx * NCOEF);
    float4 s0 = sp[0], s1 = sp[1];
    bf16x8 v;
    v[0] = (bf16_t)s0.x; v[1] = (bf16_t)s0.y; v[2] = (bf16_t)s0.z; v[3] = (bf16_t)s0.w;
    v[4] = (bf16_t)s1.x; v[5] = (bf16_t)s1.y; v[6] = (bf16_t)s1.z; v[7] = (bf16_t)s1.w;
    *(bf16x8*)(wrow + DIM + j * NCOEF) = v;
}

// ---------- layer-0 A build: A[row] = [gelu(x) bf16 x1024 | bases bf16 x8192] ----------
__global__ void prep_A(const float* __restrict__ x, bf16_t* __restrict__ A,
                       const float* __restrict__ gp, int R) {
    const int t = threadIdx.x;
    const float g0 = gp[0];
    const float invh = 1.0f / (gp[1] - gp[0]);
    for (int row = blockIdx.x; row < R; row += gridDim.x) {
        f32x4 v = *(const f32x4*)(x + (size_t)row * DIM + t * 4);
        bf16_t* Ar = A + (size_t)row * KTOT;
        bf16x4 ge;
#pragma unroll
        for (int k = 0; k < 4; k++) ge[k] = (bf16_t)gelu_exact(v[k]);
        *(bf16x4*)(Ar + t * 4) = ge;
#pragma unroll
        for (int k = 0; k < 4; k++) {
            uint64_t lo, hi;
            union { uint64_t u[2]; uint4 q; } o;
            spline8(v[k], g0, invh, lo, hi);
            o.u[0] = lo; o.u[1] = hi;
            *(uint4*)(Ar + DIM + (t * 4 + k) * NCOEF) = o.q;
        }
    }
}

// =====================================================================
// 8-phase GEMM (m201 template port): BM=BN=256, BK=64, 8 waves (2Mx4N).
// LDS: per operand 2 bufs x 2 halves x [2 kplanes][128 rows][32 K] = 64KB.
// Even tile -> buf0, odd -> buf1 (static). Half staged = 2 gl_lds16/thread.
// Iter = 2 K-tiles = 8 phases. Phase: {ds_reads; stage 1 half; BAR;
// lgkm(0); sched_barrier; setprio(1); 16 MFMA (one C-quadrant, K=64);
// setprio(0); [vmcnt(4) gate at ph4/ph8]; BAR}.
// Quadrants per tile: (r0c0)(r1c0)(r1c1)(r0c1); reads 12/8/4/0 per phase.
// Stage rota ph1..8: Bh0(T+1) Bh1(T+1) Ah0(T+2) Ah1(T+2) Bh0(T+2)
//                    Bh1(T+2) Ah0(T+3) Ah1(T+3).
// Hazards audited: every LDS overwrite is barrier-separated from its last
// read (reads complete at lgkm(0) before trailing BAR); gates vmcnt(4)
// drain exactly the halves needed by the next read point (2-6 halves in
// flight, never drained to 0 mid-loop).
// =====================================================================

#define STR2(x) #x
#define GATEV(N) asm volatile("s_waitcnt vmcnt(" STR2(N) ")" ::: "memory");
#define LGKM0    asm volatile("s_waitcnt lgkmcnt(0)" ::: "memory");
#define BAR() { __builtin_amdgcn_s_barrier(); asm volatile("" ::: "memory"); }

#define RD_A(DST, BO, G) { \
    const bf16_t* p_ = ldsA + (BO) + aOffBase + (G) * 2048; \
    DST[0][0] = *(const bf16x8*)(p_);        DST[1][0] = *(const bf16x8*)(p_ + 512); \
    DST[2][0] = *(const bf16x8*)(p_ + 1024); DST[3][0] = *(const bf16x8*)(p_ + 1536); \
    DST[0][1] = *(const bf16x8*)(p_ + 4096); DST[1][1] = *(const bf16x8*)(p_ + 4608); \
    DST[2][1] = *(const bf16x8*)(p_ + 5120); DST[3][1] = *(const bf16x8*)(p_ + 5632); }

#define RD_B(DST, BO, CG) { \
    const bf16_t* p_ = ldsB + (BO) + bOffBase + (CG) * 1024; \
    DST[0][0] = *(const bf16x8*)(p_);        DST[1][0] = *(const bf16x8*)(p_ + 512); \
    DST[0][1] = *(const bf16x8*)(p_ + 4096); DST[1][1] = *(const bf16x8*)(p_ + 4608); }

#define STG_A(TILE, HALF) { \
    const bf16_t* s_ = AgS + (size_t)(HALF) * (128 * (size_t)KTOT) + (size_t)(TILE) * 64; \
    bf16_t* d_ = ldsA + (((TILE) & 1) * 16384) + (HALF) * 8192 + tid * 8; \
    gl_lds16(s_, d_); gl_lds16(s_ + 32, d_ + 4096); }

#define STG_B(TILE, HALF) { \
    const bf16_t* s_ = BgS + (size_t)(HALF) * (128 * (size_t)KTOT) + (size_t)(TILE) * 64; \
    bf16_t* d_ = ldsB + (((TILE) & 1) * 16384) + (HALF) * 8192 + tid * 8; \
    gl_lds16(s_, d_); gl_lds16(s_ + 32, d_ + 4096); }

#define MFQ(G, CG, AS, BS) { \
    _Pragma("unroll") \
    for (int ks_ = 0; ks_ < 2; ks_++) \
    _Pragma("unroll") \
    for (int fr_ = 0; fr_ < 4; fr_++) \
    _Pragma("unroll") \
    for (int cf_ = 0; cf_ < 2; cf_++) \
        acc[(G) * 4 + fr_][(CG) * 2 + cf_] = __builtin_amdgcn_mfma_f32_16x16x32_bf16( \
            AS[fr_][ks_], BS[cf_][ks_], acc[(G) * 4 + fr_][(CG) * 2 + cf_], 0, 0, 0); }

#define PHX(MF, ENDG) \
    BAR() LGKM0 __builtin_amdgcn_sched_barrier(0); \
    __builtin_amdgcn_s_setprio(1); MF __builtin_amdgcn_s_setprio(0); \
    ENDG BAR()

#define ITER8(T, S12, S34, S56, S78, G4T, G8T) { \
    /* ph1: q(r0,c0) tile T */ \
    RD_A(Ar0, 0, 0) RD_B(Bc0, 0, 0) \
    if (S12) { STG_B((T) + 1, 0) } \
    PHX(MFQ(0, 0, Ar0, Bc0), ;) \
    /* ph2: q(r1,c0) */ \
    RD_A(Ar1, 0, 1) \
    if (S12) { STG_B((T) + 1, 1) } \
    PHX(MFQ(1, 0, Ar1, Bc0), ;) \
    /* ph3: q(r1,c1) */ \
    RD_B(Bc1, 0, 1) \
    if (S34) { STG_A((T) + 2, 0) } \
    PHX(MFQ(1, 1, Ar1, Bc1), ;) \
    /* ph4: q(r0,c1) + gate */ \
    if (S34) { STG_A((T) + 2, 1) } \
    PHX(MFQ(0, 1, Ar0, Bc1), G4T) \
    /* ph5: q(r0,c0) tile T+1 */ \
    RD_A(Ar0, 16384, 0) RD_B(Bc0, 16384, 0) \
    if (S56) { STG_B((T) + 2, 0) } \
    PHX(MFQ(0, 0, Ar0, Bc0), ;) \
    /* ph6: q(r1,c0) */ \
    RD_A(Ar1, 16384, 1) \
    if (S56) { STG_B((T) + 2, 1) } \
    PHX(MFQ(1, 0, Ar1, Bc0), ;) \
    /* ph7: q(r1,c1) */ \
    RD_B(Bc1, 16384, 1) \
    if (S78) { STG_A((T) + 3, 0) } \
    PHX(MFQ(1, 1, Ar1, Bc1), ;) \
    /* ph8: q(r0,c1) + gate */ \
    if (S78) { STG_A((T) + 3, 1) } \
    PHX(MFQ(0, 1, Ar0, Bc1), G8T) \
}

template<int NTK>   // K-tiles of 64 per split-K block (even)
__global__ __launch_bounds__(512, 2) void gemm_ab(
    const bf16_t* __restrict__ A,      // [rows, 9216] bf16
    const bf16_t* __restrict__ W,      // [1024, 9216] bf16
    float* __restrict__ C,             // [ksplit, rows, 1024] f32 partials
    int mmask, int mshift, int rows) {
    __shared__ __align__(16) bf16_t lds[65536];    // 128 KB
    bf16_t* __restrict__ ldsA = lds;
    bf16_t* __restrict__ ldsB = lds + 32768;

    const int tid = threadIdx.x;
    const int l = tid & 63, wv = tid >> 6;
    const int wm = wv >> 2, wn = wv & 3;           // 2M x 4N waves, 128x64 each

    // XCD-aware swizzle (grid always divisible by 8)
    const int chunk = gridDim.x >> 3;
    const int bid = blockIdx.x;
    const int wg = (bid & 7) * chunk + (bid >> 3);
    const int bm = wg & mmask;
    const int bn = (wg >> mshift) & 3;
    const int ks = wg >> (mshift + 2);
    const int row0 = bm << 8, col0 = bn << 8;
    const int koff0 = ks * (NTK * 64);

    // staging geometry: thread covers local row srow of each half;
    // source k-chunk pre-swizzled so LDS stays linear-in-tid.
    const int srow = tid >> 2;
    const int schunk = (tid & 3) ^ ((srow >> 1) & 3);
    const bf16_t* __restrict__ AgS = A + (size_t)(row0 + srow) * KTOT + koff0 + schunk * 8;
    const bf16_t* __restrict__ BgS = W + (size_t)(col0 + srow) * KTOT + koff0 + schunk * 8;

    // fragment-read bases; physical chunk = (l>>4) ^ ((row>>1)&3)
    const int l15 = l & 15;
    const int pc = (l >> 4) ^ ((l15 >> 1) & 3);
    const int aOffBase = wm * 8192 + l15 * 32 + pc * 8;
    const int bOffBase = (wn >> 1) * 8192 + (wn & 1) * 2048 + l15 * 32 + pc * 8;

    f32x4 acc[8][4] = {};
    bf16x8 Ar0[4][2], Ar1[4][2], Bc0[2][2], Bc1[2][2];

    // ---- prologue: A(0), B(0), A(1) staged (12 vmops); drain A(0),B(0) ----
    STG_A(0, 0) STG_A(0, 1)
    STG_B(0, 0) STG_B(0, 1)
    STG_A(1, 0) STG_A(1, 1)
    GATEV(4)
    BAR()

#pragma unroll 1
    for (int i = 0; i < NTK / 2 - 1; i++) {
        const int T = 2 * i;
        ITER8(T, 1, 1, 1, 1, GATEV(4), GATEV(4))
    }
    // tail iter (tiles NTK-2, NTK-1): stage only Bh(NTK-1); drain all at ph4
    ITER8(NTK - 2, 1, 0, 0, 0, GATEV(0), ;)

    float* __restrict__ Cp = C + (size_t)ks * rows * DIM;
    const int r0 = row0 + wm * 128 + (l >> 4) * 4;
    const int c0 = col0 + wn * 64 + l15;
#pragma unroll
    for (int i = 0; i < 8; i++)
#pragma unroll
        for (int j = 0; j < 4; j++)
#pragma unroll
            for (int r = 0; r < 4; r++)
                Cp[(size_t)(r0 + i * 16 + r) * DIM + c0 + j * 16] = acc[i][j][r];
}

// ---------- LN + PReLU over summed partials -> next-layer A (gelu + bases) ----------
__global__ void ln_mid_A(const float* __restrict__ h, int rows, int ksplit,
                         const float* __restrict__ g_ln, const float* __restrict__ b_ln,
                         const float* __restrict__ pa, bf16_t* __restrict__ A,
                         const float* __restrict__ gp) {
    const int tid = threadIdx.x;
    const int w = tid >> 6, l = tid & 63;
    const float a = pa[0];
    const float g0 = gp[0];
    const float invh = 1.0f / (gp[1] - gp[0]);
    __shared__ float rs[4], rq[4];
    for (int row = blockIdx.x; row < rows; row += gridDim.x) {
        f32x4 v = {0.0f, 0.0f, 0.0f, 0.0f};
        for (int ks = 0; ks < ksplit; ks++)
            v += *(const f32x4*)(h + ((size_t)ks * rows + row) * DIM + tid * 4);
        float s = v[0] + v[1] + v[2] + v[3];
        float q = v[0] * v[0] + v[1] * v[1] + v[2] * v[2] + v[3] * v[3];
#pragma unroll
        for (int o = 32; o > 0; o >>= 1) { s += __shfl_xor(s, o); q += __shfl_xor(q, o); }
        if (l == 0) { rs[w] = s; rq[w] = q; }
        __syncthreads();
        s = rs[0] + rs[1] + rs[2] + rs[3];
        q = rq[0] + rq[1] + rq[2] + rq[3];
        __syncthreads();
        float mean = s * (1.0f / DIM);
        float var = q * (1.0f / DIM) - mean * mean;
        float rstd = rsqrtf(var + LN_EPS);
        bf16_t* Ar = A + (size_t)row * KTOT;
        bf16x4 ge;
#pragma unroll
        for (int c = 0; c < 4; c++) {
            int col = tid * 4 + c;
            float yv = (v[c] - mean) * rstd * g_ln[col] + b_ln[col];
            yv = (yv >= 0.0f) ? yv : a * yv;
            ge[c] = (bf16_t)gelu_exact(yv);
            uint64_t lo, hi;
            union { uint64_t u[2]; uint4 qv; } o;
            spline8(yv, g0, invh, lo, hi);
            o.u[0] = lo; o.u[1] = hi;
            *(uint4*)(Ar + DIM + (size_t)col * NCOEF) = o.qv;
        }
        *(bf16x4*)(Ar + tid * 4) = ge;
    }
}

// ---------- final LN + PReLU -> f32 out ----------
__global__ void ln_out(const float* __restrict__ h, int rows, int ksplit,
                       const float* __restrict__ g_ln, const float* __restrict__ b_ln,
                       const float* __restrict__ pa, float* __restrict__ out) {
    const int tid = threadIdx.x;
    const int w = tid >> 6, l = tid & 63;
    const float a = pa[0];
    __shared__ float rs[4], rq[4];
    for (int row = blockIdx.x; row < rows; row += gridDim.x) {
        f32x4 v = {0.0f, 0.0f, 0.0f, 0.0f};
        for (int ks = 0; ks < ksplit; ks++)
            v += *(const f32x4*)(h + ((size_t)ks * rows + row) * DIM + tid * 4);
        float s = v[0] + v[1] + v[2] + v[3];
        float q = v[0] * v[0] + v[1] * v[1] + v[2] * v[2] + v[3] * v[3];
#pragma unroll
        for (int o = 32; o > 0; o >>= 1) { s += __shfl_xor(s, o); q += __shfl_xor(q, o); }
        if (l == 0) { rs[w] = s; rq[w] = q; }
        __syncthreads();
        s = rs[0] + rs[1] + rs[2] + rs[3];
        q = rq[0] + rq[1] + rq[2] + rq[3];
        __syncthreads();
        float mean = s * (1.0f / DIM);
        float var = q * (1.0f / DIM) - mean * mean;
        float rstd = rsqrtf(var + LN_EPS);
        f32x4 o4;
#pragma unroll
        for (int c = 0; c < 4; c++) {
            int col = tid * 4 + c;
            float yv = (v[c] - mean) * rstd * g_ln[col] + b_ln[col];
            o4[c] = (yv >= 0.0f) ? yv : a * yv;
        }
        *(f32x4*)(out + (size_t)row * DIM + tid * 4) = o4;
    }
}

// ---------- launch ----------
extern "C" void kernel_launch(void* const* d_in, const int* in_sizes, int n_in,
                              void* d_out, int out_size, void* d_ws, size_t ws_size,
                              hipStream_t stream) {
    const float* x    = (const float*)d_in[0];
    const float* bw   = (const float*)d_in[1];
    const float* sw   = (const float*)d_in[2];
    const float* ln_g = (const float*)d_in[3];
    const float* ln_b = (const float*)d_in[4];
    const float* pa   = (const float*)d_in[5];
    const float* gridK = (const float*)d_in[6];
    float* out = (float*)d_out;

    const size_t wbytes = (size_t)2 * DIM * KTOT * sizeof(bf16_t);   // 37.75 MB
    // per-slab: A = R*9216*2 B, hbuf = ksplit*R*1024*4 B
    int R = 8192, ksplit = 2;
    for (;;) {
        size_t need = wbytes + (size_t)R * KTOT * 2 + (size_t)ksplit * R * DIM * 4;
        if (need <= ws_size || R == 512) break;
        R >>= 1;
        int mt = R / 256;
        ksplit = (mt >= 32) ? 2 : (mt >= 16) ? 4 : 8;
    }
    int mtiles = R / 256;
    int mshift = 0; while ((1 << mshift) < mtiles) mshift++;
    int mmask = mtiles - 1;
    int grid = mtiles * 4 * ksplit;
    int lng = (R >= 2048) ? 2048 : R;

    char* wsc = (char*)d_ws;
    bf16_t* Wbuf = (bf16_t*)wsc;
    bf16_t* Abuf = (bf16_t*)(wsc + wbytes);
    float*  hbuf = (float*)(wsc + wbytes + (size_t)R * KTOT * 2);

    pack_w<<<(2 * DIM * DIM) / 256, 256, 0, stream>>>(bw, sw, Wbuf);

    auto launch_gemm = [&](const bf16_t* Wl, hipStream_t st) {
        if (ksplit == 2)
            gemm_ab<72><<<grid, 512, 0, st>>>(Abuf, Wl, hbuf, mmask, mshift, R);
        else if (ksplit == 4)
            gemm_ab<36><<<grid, 512, 0, st>>>(Abuf, Wl, hbuf, mmask, mshift, R);
        else
            gemm_ab<18><<<grid, 512, 0, st>>>(Abuf, Wl, hbuf, mmask, mshift, R);
    };

    const int nslab = BATCH / R;
    for (int sidx = 0; sidx < nslab; sidx++) {
        const size_t row0 = (size_t)sidx * R;
        const float* x0 = x + row0 * DIM;
        // layer 0
        prep_A<<<lng, 256, 0, stream>>>(x0, Abuf, gridK, R);
        launch_gemm(Wbuf, stream);
        ln_mid_A<<<lng, 256, 0, stream>>>(hbuf, R, ksplit, ln_g, ln_b, pa,
                                          Abuf, gridK + DIM * NKNOT);
        // layer 1
        launch_gemm(Wbuf + (size_t)DIM * KTOT, stream);
        ln_out<<<lng, 256, 0, stream>>>(hbuf, R, ksplit, ln_g + DIM, ln_b + DIM,
                                        pa + 1, out + row0 * DIM);
    }
}